// Round 1
// baseline (15723.737 us; speedup 1.0000x reference)
//
#include <hip/hip_runtime.h>

// Problem constants
#define LL   8
#define HH   4
#define QQ   64
#define DD   512
#define NN   2048
#define DFFC 2048

// ---------------------------------------------------------------------------
// Generic fp32 tiled GEMM: C = op(A) @ B (+bias per row)(+relu)(+res)
//   TRANSA=0: A is [M,K] row-major.  TRANSA=1: A stored [K,M] row-major (C = A^T B).
//   B is [K,N] row-major, C is [M,N] row-major.
//   Batched via blockIdx.z with strides sA/sB/sC (sB=0 => shared B).
//   64x64 tile, BK=16, 256 threads, 4x4 per thread.
// ---------------------------------------------------------------------------
template <int TRANSA, int RELU>
__global__ __launch_bounds__(256) void gemm_k(
    const float* __restrict__ A, const float* __restrict__ B,
    float* __restrict__ C, const float* __restrict__ bias,
    const float* __restrict__ res, int M, int N, int K,
    long sA, long sB, long sC)
{
    int bz = blockIdx.z;
    A += bz * sA;
    B += bz * sB;
    C += bz * sC;

    __shared__ float As[16][68];  // +4 pad keeps 16B alignment for b128 reads
    __shared__ float Bs[16][68];

    const int tid = threadIdx.x;
    const int tx = tid & 15;   // col group
    const int ty = tid >> 4;   // row group
    const int rowBase = blockIdx.y * 64;
    const int colBase = blockIdx.x * 64;

    float acc[4][4] = {};

    for (int k0 = 0; k0 < K; k0 += 16) {
        if (TRANSA) {
            // A stored [K, M]; load rows k, 64 consecutive m -> coalesced
            int m = tid & 63, kk = tid >> 6;
#pragma unroll
            for (int p = 0; p < 4; p++)
                As[kk + 4 * p][m] = A[(long)(k0 + kk + 4 * p) * M + rowBase + m];
        } else {
            // A stored [M, K]; 16 consecutive k per 16 lanes
            int kk = tid & 15, mm = tid >> 4;
#pragma unroll
            for (int p = 0; p < 4; p++)
                As[kk][mm + 16 * p] = A[(long)(rowBase + mm + 16 * p) * K + k0 + kk];
        }
        {
            int n = tid & 63, kk = tid >> 6;
#pragma unroll
            for (int p = 0; p < 4; p++)
                Bs[kk + 4 * p][n] = B[(long)(k0 + kk + 4 * p) * N + colBase + n];
        }
        __syncthreads();

#pragma unroll
        for (int kk = 0; kk < 16; kk++) {
            float a0 = As[kk][ty * 4 + 0];
            float a1 = As[kk][ty * 4 + 1];
            float a2 = As[kk][ty * 4 + 2];
            float a3 = As[kk][ty * 4 + 3];
            float b0 = Bs[kk][tx * 4 + 0];
            float b1 = Bs[kk][tx * 4 + 1];
            float b2 = Bs[kk][tx * 4 + 2];
            float b3 = Bs[kk][tx * 4 + 3];
            acc[0][0] += a0 * b0; acc[0][1] += a0 * b1; acc[0][2] += a0 * b2; acc[0][3] += a0 * b3;
            acc[1][0] += a1 * b0; acc[1][1] += a1 * b1; acc[1][2] += a1 * b2; acc[1][3] += a1 * b3;
            acc[2][0] += a2 * b0; acc[2][1] += a2 * b1; acc[2][2] += a2 * b2; acc[2][3] += a2 * b3;
            acc[3][0] += a3 * b0; acc[3][1] += a3 * b1; acc[3][2] += a3 * b2; acc[3][3] += a3 * b3;
        }
        __syncthreads();
    }

#pragma unroll
    for (int i = 0; i < 4; i++) {
        int r = rowBase + ty * 4 + i;
        float bv = bias ? bias[r] : 0.0f;
#pragma unroll
        for (int j = 0; j < 4; j++) {
            int c = colBase + tx * 4 + j;
            float v = acc[i][j] + bv;
            if (RELU) v = fmaxf(v, 0.0f);
            if (res) v += res[(long)r * N + c];
            C[(long)r * N + c] = v;
        }
    }
}

// ---------------------------------------------------------------------------
// rowstats: one wave (64 lanes) per score row. Computes rowmax and
// wrecip = (|max|>0.5 ? 1/max(count,1) : 0) where count = #{m : s >= max-0.5}.
// S is [H*NN, NN] row-major.
// ---------------------------------------------------------------------------
__global__ __launch_bounds__(256) void rowstats_k(
    const float* __restrict__ S, float* __restrict__ rowmax,
    float* __restrict__ wrecip)
{
    int row = blockIdx.x * 4 + (threadIdx.x >> 6);
    int lane = threadIdx.x & 63;
    const float* r = S + (long)row * NN;

    float mx = -3.402823466e38f;
    for (int m = lane; m < NN; m += 64) mx = fmaxf(mx, r[m]);
#pragma unroll
    for (int off = 32; off; off >>= 1) mx = fmaxf(mx, __shfl_xor(mx, off, 64));

    float thr = mx - 0.5f;
    int cnt = 0;
    for (int m = lane; m < NN; m += 64) cnt += (r[m] >= thr) ? 1 : 0;
#pragma unroll
    for (int off = 32; off; off >>= 1) cnt += __shfl_xor(cnt, off, 64);

    if (lane == 0) {
        rowmax[row] = mx;
        wrecip[row] = (fabsf(mx) > 0.5f) ? 1.0f / fmaxf((float)cnt, 1.0f) : 0.0f;
    }
}

// ---------------------------------------------------------------------------
// colpass: attn[:, mtile] = X[:, mtile] + sum_h sum_{n in mask col} w[n]*Y_h[:, n]
// One block per 16-column tile. 256 threads; thread t accumulates rows t and
// t+256 for all 16 columns in registers. Selected (n, w) pairs are staged in
// LDS lists per 16-row chunk, then flushed cooperatively.
// ---------------------------------------------------------------------------
__global__ __launch_bounds__(256) void colpass_k(
    const float* __restrict__ S, const float* __restrict__ rowmax,
    const float* __restrict__ wrecip, const float* __restrict__ Y,
    const float* __restrict__ X, float* __restrict__ attn)
{
    __shared__ int   cnt[16];
    __shared__ int   listN[16][16];
    __shared__ float listW[16][16];
    __shared__ float tile[256][17];

    const int mb = blockIdx.x * 16;
    const int tid = threadIdx.x;
    const int nI = tid >> 4, mI = tid & 15;

    float acc0[16], acc1[16];
#pragma unroll
    for (int c = 0; c < 16; c++) { acc0[c] = 0.0f; acc1[c] = 0.0f; }

    for (int h = 0; h < HH; h++) {
        const float* Sh  = S + (long)h * NN * NN;
        const float* Yh  = Y + (long)h * DD * NN;
        const float* rmh = rowmax + h * NN;
        const float* wrh = wrecip + h * NN;

        for (int nb = 0; nb < NN; nb += 16) {
            if (tid < 16) cnt[tid] = 0;
            __syncthreads();

            int n = nb + nI;
            float s  = Sh[(long)n * NN + mb + mI];
            float rm = rmh[n];
            float w  = wrh[n];
            if (w != 0.0f && s >= rm - 0.5f) {
                int slot = atomicAdd(&cnt[mI], 1);
                listN[mI][slot] = n;
                listW[mI][slot] = w;
            }
            __syncthreads();

#pragma unroll 1
            for (int c = 0; c < 16; c++) {
                int e = cnt[c];
#pragma unroll 1
                for (int i = 0; i < e; i++) {
                    int n2   = listN[c][i];
                    float w2 = listW[c][i];
                    acc0[c] += w2 * Yh[(long)tid * NN + n2];
                    acc1[c] += w2 * Yh[(long)(tid + 256) * NN + n2];
                }
            }
            __syncthreads();
        }
    }

    // Add residual X and write attn via LDS transpose for coalesced stores.
#pragma unroll
    for (int half = 0; half < 2; half++) {
        int dbase = half * 256;
#pragma unroll
        for (int c = 0; c < 16; c++)
            tile[tid][c] = (half ? acc1[c] : acc0[c]) + X[(long)(dbase + tid) * NN + mb + c];
        __syncthreads();
#pragma unroll
        for (int w = 0; w < 16; w++) {
            int idx = tid + 256 * w;
            int dl = idx >> 4, c = idx & 15;
            attn[(long)(dbase + dl) * NN + mb + c] = tile[dl][c];
        }
        __syncthreads();
    }
}

// ---------------------------------------------------------------------------
// Launch: 8 layers, 7 kernels each.
// Workspace (floats):
//   S      : 16777216  (64MB)  -- scores [H,N,N]; ff1 aliases this after colpass
//   KX     :   524288  ( 2MB)  -- [H,Q,N]
//   rowmax :     8192
//   wrecip :     8192
//   Y      :  4194304  (16MB)  -- [H,D,N]
//   attn   :  1048576  ( 4MB)
//   Xbuf   :  1048576  ( 4MB)
// total ~94.5 MB
// ---------------------------------------------------------------------------
extern "C" void kernel_launch(void* const* d_in, const int* in_sizes, int n_in,
                              void* d_out, int out_size, void* d_ws, size_t ws_size,
                              hipStream_t stream)
{
    const float* X0 = (const float*)d_in[0];
    const float* Kw = (const float*)d_in[1];
    const float* Vw = (const float*)d_in[2];
    const float* W1 = (const float*)d_in[3];
    const float* b1 = (const float*)d_in[4];
    const float* W2 = (const float*)d_in[5];
    const float* b2 = (const float*)d_in[6];
    float* out = (float*)d_out;

    float* ws     = (float*)d_ws;
    float* S      = ws;                  // 16777216 floats
    float* ff1    = ws;                  // alias: DFF*NN = 4194304 <= |S|
    float* KX     = ws + 16777216;       // 524288
    float* rowmax = KX + 524288;         // 8192
    float* wrecip = rowmax + 8192;       // 8192
    float* Y      = wrecip + 8192;       // 4194304
    float* attn   = Y + 4194304;         // 1048576
    float* Xbuf   = attn + 1048576;      // 1048576

    const float* Xc = X0;
    for (int li = 0; li < LL; li++) {
        // 1) KX = K_l @ X   [H*Q=256, N], K=D
        gemm_k<0, 0><<<dim3(NN / 64, 256 / 64, 1), 256, 0, stream>>>(
            Kw + (long)li * HH * QQ * DD, Xc, KX, nullptr, nullptr,
            HH * QQ, NN, DD, 0, 0, 0);

        // 2) S_h = KX_h^T @ KX_h   [N, N], K=Q, batch H
        gemm_k<1, 0><<<dim3(NN / 64, NN / 64, HH), 256, 0, stream>>>(
            KX, KX, S, nullptr, nullptr,
            NN, NN, QQ, (long)QQ * NN, (long)QQ * NN, (long)NN * NN);

        // 3) per-row max / weight-reciprocal
        rowstats_k<<<dim3(HH * NN / 4), 256, 0, stream>>>(S, rowmax, wrecip);

        // 4) Y_h = V_h @ X   [D, N], K=D, batch H (B shared: sB=0)
        gemm_k<0, 0><<<dim3(NN / 64, DD / 64, HH), 256, 0, stream>>>(
            Vw + (long)li * HH * DD * DD, Xc, Y, nullptr, nullptr,
            DD, NN, DD, (long)DD * DD, 0, (long)DD * NN);

        // 5) attn = X + sparse-combine(Y, mask)
        colpass_k<<<dim3(NN / 16), 256, 0, stream>>>(S, rowmax, wrecip, Y, Xc, attn);

        // 6) ff1 = relu(W1 @ attn + b1)   [DFF, N], K=D
        gemm_k<0, 1><<<dim3(NN / 64, DFFC / 64, 1), 256, 0, stream>>>(
            W1 + (long)li * DFFC * DD, attn, ff1, b1 + li * DFFC, nullptr,
            DFFC, NN, DD, 0, 0, 0);

        // 7) X' = W2 @ ff1 + b2 + attn   [D, N], K=DFF
        float* Xn = (li == LL - 1) ? out : Xbuf;
        gemm_k<0, 0><<<dim3(NN / 64, DD / 64, 1), 256, 0, stream>>>(
            W2 + (long)li * DD * DFFC, ff1, Xn, b2 + li * DD, attn,
            DD, NN, DFFC, 0, 0, 0);

        Xc = Xn;
    }
}

// Round 2
// 4372.822 us; speedup vs baseline: 3.5958x; 3.5958x over previous
//
#include <hip/hip_runtime.h>

// Problem constants
#define LL   8
#define HH   4
#define QQ   64
#define DD   512
#define NN   2048
#define DFFC 2048
#define ENTRY_CAP (1 << 18)

// ---------------------------------------------------------------------------
// Generic fp32 tiled GEMM: C = op(A) @ op(B) (+bias per COLUMN)(+relu)(+res)
//   TRANSA=0: A stored [M,K] ld=lda.  TRANSA=1: A stored [K,M] (C += A^T B).
//   TRANSB=0: B stored [K,N] ld=ldb.  TRANSB=1: B stored [N,K] (op(B)=B^T).
//   C is [M,N] ld=ldc row-major. res same layout as C. bias indexed by col.
//   Batched via blockIdx.z with strides sA/sB/sC (0 => shared operand).
//   64x64 tile, BK=16, 256 threads, 4x4 per thread.
// ---------------------------------------------------------------------------
template <int TRANSA, int TRANSB, int RELU>
__global__ __launch_bounds__(256) void gemm_k(
    const float* __restrict__ A, const float* __restrict__ B,
    float* __restrict__ C, const float* __restrict__ bias,
    const float* __restrict__ res, int M, int N, int K,
    int lda, int ldb, int ldc, long sA, long sB, long sC)
{
    int bz = blockIdx.z;
    A += bz * sA;
    B += bz * sB;
    C += bz * sC;

    __shared__ float As[16][68];
    __shared__ float Bs[16][68];

    const int tid = threadIdx.x;
    const int tx = tid & 15;   // col group
    const int ty = tid >> 4;   // row group
    const int rowBase = blockIdx.y * 64;
    const int colBase = blockIdx.x * 64;

    float acc[4][4] = {};

    for (int k0 = 0; k0 < K; k0 += 16) {
        if (TRANSA) {
            // A stored [K, M]; rows k, 64 consecutive m -> coalesced
            int m = tid & 63, kk = tid >> 6;
#pragma unroll
            for (int p = 0; p < 4; p++)
                As[kk + 4 * p][m] = A[(long)(k0 + kk + 4 * p) * lda + rowBase + m];
        } else {
            // A stored [M, K]; 16 consecutive k per lane group
            int kk = tid & 15, mm = tid >> 4;
#pragma unroll
            for (int p = 0; p < 4; p++)
                As[kk][mm + 16 * p] = A[(long)(rowBase + mm + 16 * p) * lda + k0 + kk];
        }
        if (TRANSB) {
            // B stored [N, K]; 16 consecutive k per lane group
            int kk = tid & 15, nn = tid >> 4;
#pragma unroll
            for (int p = 0; p < 4; p++)
                Bs[kk][nn + 16 * p] = B[(long)(colBase + nn + 16 * p) * ldb + k0 + kk];
        } else {
            // B stored [K, N]; rows k, 64 consecutive n -> coalesced
            int n = tid & 63, kk = tid >> 6;
#pragma unroll
            for (int p = 0; p < 4; p++)
                Bs[kk + 4 * p][n] = B[(long)(k0 + kk + 4 * p) * ldb + colBase + n];
        }
        __syncthreads();

#pragma unroll
        for (int kk = 0; kk < 16; kk++) {
            float a0 = As[kk][ty * 4 + 0];
            float a1 = As[kk][ty * 4 + 1];
            float a2 = As[kk][ty * 4 + 2];
            float a3 = As[kk][ty * 4 + 3];
            float b0 = Bs[kk][tx * 4 + 0];
            float b1 = Bs[kk][tx * 4 + 1];
            float b2 = Bs[kk][tx * 4 + 2];
            float b3 = Bs[kk][tx * 4 + 3];
            acc[0][0] += a0 * b0; acc[0][1] += a0 * b1; acc[0][2] += a0 * b2; acc[0][3] += a0 * b3;
            acc[1][0] += a1 * b0; acc[1][1] += a1 * b1; acc[1][2] += a1 * b2; acc[1][3] += a1 * b3;
            acc[2][0] += a2 * b0; acc[2][1] += a2 * b1; acc[2][2] += a2 * b2; acc[2][3] += a2 * b3;
            acc[3][0] += a3 * b0; acc[3][1] += a3 * b1; acc[3][2] += a3 * b2; acc[3][3] += a3 * b3;
        }
        __syncthreads();
    }

#pragma unroll
    for (int i = 0; i < 4; i++) {
        int r = rowBase + ty * 4 + i;
#pragma unroll
        for (int j = 0; j < 4; j++) {
            int c = colBase + tx * 4 + j;
            float v = acc[i][j];
            if (bias) v += bias[c];
            if (RELU) v = fmaxf(v, 0.0f);
            if (res) v += res[(long)r * ldc + c];
            C[(long)r * ldc + c] = v;
        }
    }
}

// ---------------------------------------------------------------------------
// extract: one wave per score row (h,n). Computes rowmax, count, wrecip and
// emits packed entries (row<<11 | m) for mask hits of active rows.
// S is [H*NN, NN] row-major.
// ---------------------------------------------------------------------------
__global__ __launch_bounds__(256) void extract_k(
    const float* __restrict__ S, float* __restrict__ wrecip,
    unsigned int* __restrict__ entries, int* __restrict__ counter)
{
    int row = blockIdx.x * 4 + (threadIdx.x >> 6);
    int lane = threadIdx.x & 63;
    const float* r = S + (long)row * NN;

    float mx = -3.402823466e38f;
    for (int m = lane; m < NN; m += 64) mx = fmaxf(mx, r[m]);
#pragma unroll
    for (int off = 32; off; off >>= 1) mx = fmaxf(mx, __shfl_xor(mx, off, 64));

    float thr = mx - 0.5f;
    bool active = fabsf(mx) > 0.5f;
    int cnt = 0;
    for (int m = lane; m < NN; m += 64) {
        if (r[m] >= thr) {
            cnt++;
            if (active) {
                unsigned pos = (unsigned)atomicAdd(counter, 1);
                if (pos < ENTRY_CAP)
                    entries[pos] = ((unsigned)row << 11) | (unsigned)m;
            }
        }
    }
#pragma unroll
    for (int off = 32; off; off >>= 1) cnt += __shfl_xor(cnt, off, 64);

    if (lane == 0)
        wrecip[row] = active ? 1.0f / fmaxf((float)cnt, 1.0f) : 0.0f;
}

// ---------------------------------------------------------------------------
// apply: grid-stride over entries; attnT[m][:] += w * Yt[row][:]
// Yt is [H*NN, DD] row-major; attnT is [NN, DD]. Coalesced fp32 atomics.
// ---------------------------------------------------------------------------
__global__ __launch_bounds__(256) void apply_k(
    const unsigned int* __restrict__ entries, const int* __restrict__ counter,
    const float* __restrict__ wrecip, const float* __restrict__ Yt,
    float* __restrict__ attnT)
{
    int cnt = *counter;
    if (cnt > ENTRY_CAP) cnt = ENTRY_CAP;
    int tid = threadIdx.x;
    for (int e = blockIdx.x; e < cnt; e += gridDim.x) {
        unsigned v = entries[e];
        int m   = v & 2047;
        int row = v >> 11;              // h*NN + n
        float w = wrecip[row];
        const float* y = Yt + (long)row * DD;
        float* a = attnT + (long)m * DD;
        atomicAdd(&a[tid],       w * y[tid]);
        atomicAdd(&a[tid + 256], w * y[tid + 256]);
    }
}

// ---------------------------------------------------------------------------
// transpose: src [R,C] -> dst [C,R]. 32x32 LDS tiles, 256 threads.
// ---------------------------------------------------------------------------
__global__ __launch_bounds__(256) void transpose_k(
    const float* __restrict__ src, float* __restrict__ dst, int R, int C)
{
    __shared__ float t[32][33];
    int tx = threadIdx.x & 31, ty = threadIdx.x >> 5;   // ty 0..7
    int c0 = blockIdx.x * 32, r0 = blockIdx.y * 32;
#pragma unroll
    for (int k = 0; k < 4; k++)
        t[ty + 8 * k][tx] = src[(long)(r0 + ty + 8 * k) * C + c0 + tx];
    __syncthreads();
#pragma unroll
    for (int k = 0; k < 4; k++)
        dst[(long)(c0 + ty + 8 * k) * R + r0 + tx] = t[tx][ty + 8 * k];
}

__global__ void zero_k(int* counters)
{
    if (threadIdx.x < LL) counters[threadIdx.x] = 0;
}

// ---------------------------------------------------------------------------
// Workspace layout (floats):
//   region0 : 16777216 (64MB)  S [H,N,N]; Yt [H,N,D] and ff1T [N,DFF] alias it
//             (both 4194304 floats, live only after S is dead)
//   KX      :   524288         [H*Q, N]
//   wrecip  :     8192
//   attnT   :  1048576         [N, D]
//   XbufA   :  1048576         [N, D]
//   XbufB   :  1048576
//   entries :   262144 (uint)
//   counters:       64
// total ~83 MB
// ---------------------------------------------------------------------------
extern "C" void kernel_launch(void* const* d_in, const int* in_sizes, int n_in,
                              void* d_out, int out_size, void* d_ws, size_t ws_size,
                              hipStream_t stream)
{
    const float* X0 = (const float*)d_in[0];
    const float* Kw = (const float*)d_in[1];
    const float* Vw = (const float*)d_in[2];
    const float* W1 = (const float*)d_in[3];
    const float* b1 = (const float*)d_in[4];
    const float* W2 = (const float*)d_in[5];
    const float* b2 = (const float*)d_in[6];
    float* out = (float*)d_out;

    float* ws      = (float*)d_ws;
    float* S       = ws;                         // 16777216
    float* Yt      = ws;                         // alias (after extract)
    float* ff1T    = ws;                         // alias (after apply)
    float* KX      = ws + 16777216;              // 524288
    float* wrecip  = KX + 524288;                // 8192
    float* attnT   = wrecip + 8192;              // 1048576
    float* XbufA   = attnT + 1048576;            // 1048576
    float* XbufB   = XbufA + 1048576;            // 1048576
    unsigned int* entries = (unsigned int*)(XbufB + 1048576);  // 262144
    int* counters  = (int*)(entries + ENTRY_CAP);

    zero_k<<<1, 64, 0, stream>>>(counters);

    // XT0 = X0^T  [N, D]
    transpose_k<<<dim3(NN / 32, DD / 32), 256, 0, stream>>>(X0, XbufA, DD, NN);

    float* Xc = XbufA;
    for (int li = 0; li < LL; li++) {
        float* Xn = (li & 1) ? XbufA : XbufB;

        // 1) KX = K_l @ X = K_l @ XT^T   [H*Q, N]
        gemm_k<0, 1, 0><<<dim3(NN / 64, (HH * QQ) / 64, 1), 256, 0, stream>>>(
            Kw + (long)li * HH * QQ * DD, Xc, KX, nullptr, nullptr,
            HH * QQ, NN, DD, DD, DD, NN, 0, 0, 0);

        // 2) S_h = KX_h^T @ KX_h   [N, N] batch H
        gemm_k<1, 0, 0><<<dim3(NN / 64, NN / 64, HH), 256, 0, stream>>>(
            KX, KX, S, nullptr, nullptr,
            NN, NN, QQ, NN, NN, NN,
            (long)QQ * NN, (long)QQ * NN, (long)NN * NN);

        // 3) row stats + sparse mask extraction
        extract_k<<<dim3(HH * NN / 4), 256, 0, stream>>>(S, wrecip, entries, counters + li);

        // 4) Yt_h = XT @ V_h^T   [N, D] batch H (A shared; aliases dead S)
        gemm_k<0, 1, 0><<<dim3(DD / 64, NN / 64, HH), 256, 0, stream>>>(
            Xc, Vw + (long)li * HH * DD * DD, Yt, nullptr, nullptr,
            NN, DD, DD, DD, DD, DD,
            0, (long)DD * DD, (long)NN * DD);

        // 5) attnT = XT; then attnT[m] += w * Yt[row]
        hipMemcpyAsync(attnT, Xc, (size_t)NN * DD * sizeof(float),
                       hipMemcpyDeviceToDevice, stream);
        apply_k<<<dim3(512), 256, 0, stream>>>(entries, counters + li, wrecip, Yt, attnT);

        // 6) ff1T = relu(attnT @ W1^T + b1)   [N, DFF] (aliases dead Yt)
        gemm_k<0, 1, 1><<<dim3(DFFC / 64, NN / 64, 1), 256, 0, stream>>>(
            attnT, W1 + (long)li * DFFC * DD, ff1T, b1 + (long)li * DFFC, nullptr,
            NN, DFFC, DD, DD, DD, DFFC, 0, 0, 0);

        // 7) XT' = ff1T @ W2^T + b2 + attnT   [N, D]
        gemm_k<0, 1, 0><<<dim3(DD / 64, NN / 64, 1), 256, 0, stream>>>(
            ff1T, W2 + (long)li * DD * DFFC, Xn, b2 + (long)li * DD, attnT,
            NN, DD, DFFC, DFFC, DFFC, DD, 0, 0, 0);

        Xc = Xn;
    }

    // out = XT_final^T  [D, N]
    transpose_k<<<dim3(DD / 32, NN / 32), 256, 0, stream>>>(Xc, out, NN, DD);
}